// Round 3
// baseline (624.773 us; speedup 1.0000x reference)
//
#include <hip/hip_runtime.h>
#include <hip/hip_cooperative_groups.h>
#include <stdint.h>
#include <math.h>

namespace cg = cooperative_groups;

#define N_CLS    81
#define TOPK     1000
#define LISTCAP  (1u << 21)     // 2M candidate keys (16 MB)
#define CAP2     16384          // final selection capacity
#define SCORE_TH 0.05f
#define IMG_W    1333.0f
#define IMG_H    800.0f
#define GH_REP   16             // coarse-hist replicas (atomic spread)

// coarse bucket = float_bits >> 19; ghist index = (bits>>19) - GH_BASE in [0,128)
#define GH_BASE  1905

// workspace layout (byte offsets)
#define OFF_CNT    0                       // u32 total candidates
#define OFF_CNT2   8                       // u32 selected count
#define OFF_GH     64                      // u32[GH_REP][128] coarse hist (8192 B)
#define OFF_RH     8256                    // u32[1024] refined hist (4096 B)
#define OFF_SORTED 12352                   // u64[1000] sorted keys (0 sentinel)
#define MEMSET_BYTES 20352
#define OFF_SEL    20480                   // u64[LISTCAP]
#define OFF_SEL2   16797696                // u64[CAP2]
#define OFF_BOX    16928768                // f32[1000*4]
#define OFF_SCORE  16944768                // f32[1000]
#define OFF_CLS    16948768                // i32[1000]
#define OFF_MASK   16952832                // u64[1000*16] conflict bit matrix

typedef unsigned long long u64;

// ------- K1: single pass: softmax, coarse hist (LDS), compact all p>0.05 -------
// NOTE: arithmetic (loads, butterfly order, expf, e/s) must stay bit-identical
// to the round-1/2 version which matched the reference with absmax 0.0.
__global__ __launch_bounds__(256) void k_pass1(
        const float* __restrict__ logits, int nrows,
        u64* __restrict__ sel, unsigned* __restrict__ cnt,
        unsigned* __restrict__ ghist) {
    __shared__ unsigned lh[128];
    __shared__ u64 cbuf[1024];
    __shared__ unsigned lcnt, gbase;
    int tid = threadIdx.x, wv = tid >> 6, ln = tid & 63;
    for (int i = tid; i < 128; i += 256) lh[i] = 0;
    if (tid == 0) lcnt = 0;
    __syncthreads();

    int stride = gridDim.x * 16;
    for (int base = blockIdx.x * 16 + wv * 4; base < nrows; base += stride) {
        int nr = nrows - base; if (nr > 4) nr = 4;   // wave-uniform
        float v0[4], v1[4], m[4], e0[4], e1[4], s[4];
        #pragma unroll
        for (int k = 0; k < 4; k++) {
            bool ok = (k < nr);
            const float* rp = logits + (size_t)(ok ? base + k : base) * N_CLS;
            v0[k] = ok ? rp[ln] : 0.0f;
            v1[k] = (ok && ln < N_CLS - 64) ? rp[64 + ln] : -INFINITY;
        }
        #pragma unroll
        for (int k = 0; k < 4; k++) m[k] = fmaxf(v0[k], v1[k]);
        #pragma unroll
        for (int off = 32; off > 0; off >>= 1)
            #pragma unroll
            for (int k = 0; k < 4; k++) m[k] = fmaxf(m[k], __shfl_xor(m[k], off));
        #pragma unroll
        for (int k = 0; k < 4; k++) {
            e0[k] = expf(v0[k] - m[k]);
            e1[k] = (ln < N_CLS - 64) ? expf(v1[k] - m[k]) : 0.0f;
            s[k] = e0[k] + e1[k];
        }
        #pragma unroll
        for (int off = 32; off > 0; off >>= 1)
            #pragma unroll
            for (int k = 0; k < 4; k++) s[k] += __shfl_xor(s[k], off);

        #pragma unroll
        for (int k = 0; k < 4; k++) {
            if (k >= nr) break;                     // wave-uniform
            float p0 = e0[k] / s[k];
            float p1 = e1[k] / s[k];
            bool c0 = (k < nr) && (ln != 0) && (p0 > SCORE_TH);
            bool c1 = (k < nr) && (ln < N_CLS - 64) && (p1 > SCORE_TH);
            unsigned fb0 = __float_as_uint(p0), fb1 = __float_as_uint(p1);
            if (c0) atomicAdd(&lh[(fb0 >> 19) - GH_BASE], 1u);
            if (c1) atomicAdd(&lh[(fb1 >> 19) - GH_BASE], 1u);
            u64 b0 = __ballot(c0), b1 = __ballot(c1);
            int n0 = __popcll(b0), n1 = __popcll(b1);
            if (n0 + n1 == 0) continue;
            unsigned wb = 0;
            if (ln == 0) wb = atomicAdd(&lcnt, (unsigned)(n0 + n1));
            wb = __shfl(wb, 0);
            u64 lt = (1ull << ln) - 1ull;
            unsigned flat = (unsigned)(base + k) * N_CLS + (unsigned)ln;
            if (c0) {
                unsigned pos = wb + (unsigned)__popcll(b0 & lt);
                u64 key = ((u64)fb0 << 32) | (u64)(0xFFFFFFu - flat);
                if (pos < 1024) cbuf[pos] = key;
                else { unsigned gp = atomicAdd(cnt, 1u); if (gp < LISTCAP) sel[gp] = key; }
            }
            if (c1) {
                unsigned pos = wb + (unsigned)n0 + (unsigned)__popcll(b1 & lt);
                u64 key = ((u64)fb1 << 32) | (u64)(0xFFFFFFu - (flat + 64u));
                if (pos < 1024) cbuf[pos] = key;
                else { unsigned gp = atomicAdd(cnt, 1u); if (gp < LISTCAP) sel[gp] = key; }
            }
        }
    }
    __syncthreads();
    unsigned* gh = ghist + (blockIdx.x & (GH_REP - 1)) * 128;
    for (int i = tid; i < 128; i += 256) {
        unsigned v = lh[i];
        if (v) atomicAdd(&gh[i], v);
    }
    unsigned total = lcnt; if (total > 1024u) total = 1024u;
    if (tid == 0) gbase = atomicAdd(cnt, total);
    __syncthreads();
    unsigned gb = gbase;
    for (unsigned i = tid; i < total; i += 256) {
        unsigned gp = gb + i;
        if (gp < LISTCAP) sel[gp] = cbuf[i];
    }
}

// ------- K2: fused tail (refine -> threshold -> compact -> rank -> decode ->
//             conflict matrix -> greedy NMS -> output), cooperative launch -------
__global__ __launch_bounds__(1024, 4) void k_tail(
        const float* __restrict__ boxes,
        const u64* __restrict__ sel, const unsigned* __restrict__ cnt,
        const unsigned* __restrict__ ghist, unsigned* __restrict__ rhist,
        u64* __restrict__ sel2, unsigned* __restrict__ cnt2,
        u64* __restrict__ sorted,
        float* __restrict__ boxK, float* __restrict__ scoreK, int* __restrict__ clsK,
        u64* __restrict__ mask, float* __restrict__ out) {
    cg::grid_group grid = cg::this_grid();
    __shared__ u64 ch[2048];                 // 16 KB, reused across phases
    __shared__ u64 words[16];
    __shared__ int sB, sChg;
    unsigned* cA = (unsigned*)ch;            // 4096 u32 view
    int tid = threadIdx.x, bid = blockIdx.x;
    int ln = tid & 63, wvi = tid >> 6;
    unsigned gtid = bid * 1024u + tid;
    unsigned gstride = gridDim.x * 1024u;

    unsigned M = *cnt; if (M > LISTCAP) M = LISTCAP;

    // ---- find coarse bucket B containing rank TOPK (per-block, redundant) ----
    if (tid < 128) {
        unsigned c = 0;
        #pragma unroll
        for (int r = 0; r < GH_REP; r++) c += ghist[r * 128 + tid];
        cA[tid] = c;
    }
    __syncthreads();
    {   // suffix-sum over 128 bins, ping-pong cA[0..127] <-> cA[128..255]
        unsigned* s0 = cA; unsigned* s1 = cA + 128;
        for (int off = 1; off < 128; off <<= 1) {
            if (tid < 128) s1[tid] = s0[tid] + ((tid + off < 128) ? s0[tid + off] : 0u);
            __syncthreads();
            unsigned* t = s0; s0 = s1; s1 = t;
        }
        if (tid == 0) sB = -1;
        __syncthreads();
        if (tid < 128 && s0[tid] >= TOPK) atomicMax(&sB, tid);
        __syncthreads();
        int B = sB;
        unsigned c_above = (B >= 0 && B < 127) ? s0[B + 1] : 0u;
        __syncthreads();   // done with this LDS view

        // ---- Phase A: refined 1024-bin histogram of bucket B ----
        if (B >= 0) {
            cA[tid] = 0;  // lh[tid]
            __syncthreads();
            unsigned Bb = (unsigned)(B + GH_BASE);
            for (unsigned i = gtid; i < M; i += gstride) {
                unsigned bits = (unsigned)(sel[i] >> 32);
                if ((bits >> 19) == Bb) atomicAdd(&cA[(bits >> 9) & 1023u], 1u);
            }
            __syncthreads();
            unsigned v = cA[tid];
            if (v) atomicAdd(&rhist[tid], v);
        }
        __threadfence();
        grid.sync();

        // ---- Phase B: exact threshold tb via suffix-sum over rhist ----
        unsigned* a = cA; unsigned* b = cA + 1024;
        a[tid] = rhist[tid];
        __syncthreads();
        unsigned* src = a; unsigned* dst = b;
        for (int off = 1; off < 1024; off <<= 1) {
            dst[tid] = src[tid] + ((tid + off < 1024) ? src[tid + off] : 0u);
            __syncthreads();
            unsigned* t = src; src = dst; dst = t;
        }
        if (tid == 0) sB = -1;
        __syncthreads();
        if (B >= 0 && (c_above + src[tid] >= TOPK)) atomicMax(&sB, tid);
        __syncthreads();
        unsigned tb = 0;
        if (B >= 0) {
            int sb = sB; if (sb < 0) sb = 0;
            tb = ((unsigned)(B + GH_BASE) << 19) | ((unsigned)sb << 9);
        }
        __syncthreads();

        // compact keys >= tb into sel2
        for (unsigned ib = bid * 1024u; ib < M; ib += gstride) {
            unsigned i = ib + tid;
            bool act = (i < M);
            u64 key = act ? sel[i] : 0ull;
            bool c = act && ((unsigned)(key >> 32) >= tb);
            u64 bal = __ballot(c);
            int n = __popcll(bal);
            if (n) {
                unsigned wb = 0;
                if (ln == 0) wb = atomicAdd(cnt2, (unsigned)n);
                wb = __shfl(wb, 0);
                if (c) {
                    unsigned pos = wb + (unsigned)__popcll(bal & ((1ull << ln) - 1ull));
                    if (pos < CAP2) sel2[pos] = key;
                }
            }
        }
    }
    __threadfence();
    grid.sync();

    // ---- Phase C: exact rank by counting (keys distinct) ----
    unsigned S = *cnt2; if (S > CAP2) S = CAP2;
    if (bid * 1024u < S) {
        u64 my = (gtid < S) ? sel2[gtid] : 0ull;
        unsigned r = 0;
        for (unsigned c0 = 0; c0 < S; c0 += 2048) {
            unsigned n = S - c0; if (n > 2048u) n = 2048u;
            __syncthreads();
            for (unsigned i = tid; i < n; i += 1024) ch[i] = sel2[c0 + i];
            __syncthreads();
            if (gtid < S)
                for (unsigned j = 0; j < n; j++) r += (ch[j] > my) ? 1u : 0u;
        }
        if (gtid < S && r < TOPK) sorted[r] = my;
    }
    __threadfence();
    grid.sync();

    // ---- Phase D: decode keys, gather + clip boxes ----
    if (gtid < TOPK) {
        u64 key = sorted[gtid];
        if (key != 0ull) {
            float sc = __uint_as_float((unsigned)(key >> 32));
            unsigned fi = 0xFFFFFFu - (unsigned)(key & 0xFFFFFFFFull);
            unsigned prop = fi / N_CLS;
            int cls = (int)(fi - prop * N_CLS);
            const float* bp = boxes + (size_t)prop * 4;
            boxK[gtid * 4 + 0] = fminf(fmaxf(bp[0], 0.0f), IMG_W - 1.0f);
            boxK[gtid * 4 + 1] = fminf(fmaxf(bp[1], 0.0f), IMG_H - 1.0f);
            boxK[gtid * 4 + 2] = fminf(fmaxf(bp[2], 0.0f), IMG_W - 1.0f);
            boxK[gtid * 4 + 3] = fminf(fmaxf(bp[3], 0.0f), IMG_H - 1.0f);
            scoreK[gtid] = sc;
            clsK[gtid] = cls;
        } else {
            boxK[gtid * 4 + 0] = 0.0f; boxK[gtid * 4 + 1] = 0.0f;
            boxK[gtid * 4 + 2] = 0.0f; boxK[gtid * 4 + 3] = 0.0f;
            scoreK[gtid] = 0.0f;
            clsK[gtid] = -1;
        }
    }
    __threadfence();
    grid.sync();

    // ---- Phase E: conflict bit-matrix (IoU > 0.5 && same class) ----
    if (gtid < TOPK * 16u) {
        int i = (int)(gtid >> 4), w = (int)(gtid & 15u);
        float x1 = boxK[i * 4 + 0], y1 = boxK[i * 4 + 1];
        float x2 = boxK[i * 4 + 2], y2 = boxK[i * 4 + 3];
        int ci = clsK[i];
        float ai = (x2 - x1) * (y2 - y1);
        u64 m = 0;
        int jbase = w << 6;
        for (int jj = 0; jj < 64; jj++) {
            int j = jbase + jj;
            if (j >= TOPK) break;
            float u1 = boxK[j * 4 + 0], w1 = boxK[j * 4 + 1];
            float u2 = boxK[j * 4 + 2], w2 = boxK[j * 4 + 3];
            float aj = (u2 - u1) * (w2 - w1);
            float ww = fmaxf(fminf(x2, u2) - fmaxf(x1, u1), 0.0f);
            float hh = fmaxf(fminf(y2, w2) - fmaxf(y1, w1), 0.0f);
            float inter = ww * hh;
            float iou = inter / (ai + aj - inter + 1e-9f);
            if (iou > 0.5f && ci == clsK[j]) m |= (1ull << jj);
        }
        mask[(size_t)i * 16 + w] = m;
    }
    __threadfence();
    grid.sync();

    // ---- Phase F: Jacobi fixed-point of greedy NMS + output (block 0 only) ----
    if (bid != 0) return;
    bool valid = (tid < TOPK) && (scoreK[tid] > 0.0f);
    u64 row[16];
    #pragma unroll
    for (int w = 0; w < 16; w++)
        row[w] = (tid < TOPK) ? mask[(size_t)tid * 16 + w] : 0ull;
    u64 lowmask = (1ull << ln) - 1ull;
    bool keep = valid;
    for (int it = 0; it < 1024; ++it) {
        u64 b = __ballot(keep);
        if (ln == 0) words[wvi] = b;
        if (tid == 0) sChg = 0;
        __syncthreads();
        u64 sup = 0;
        for (int w = 0; w <= wvi; w++) {
            u64 kw = words[w];
            if (w == wvi) kw &= lowmask;
            sup |= row[w] & kw;
        }
        bool nk = valid && (sup == 0ull);
        if (nk != keep) sChg = 1;
        keep = nk;
        __syncthreads();
        if (!sChg) break;
    }
    if (tid < TOPK) {
        float x1 = boxK[tid * 4 + 0], y1 = boxK[tid * 4 + 1];
        float x2 = boxK[tid * 4 + 2], y2 = boxK[tid * 4 + 3];
        float sc = scoreK[tid];
        out[tid * 5 + 0] = keep ? x1 : 0.0f;
        out[tid * 5 + 1] = keep ? y1 : 0.0f;
        out[tid * 5 + 2] = keep ? x2 : 0.0f;
        out[tid * 5 + 3] = keep ? y2 : 0.0f;
        out[tid * 5 + 4] = keep ? sc : 0.0f;
    }
}

extern "C" void kernel_launch(void* const* d_in, const int* in_sizes, int n_in,
                              void* d_out, int out_size, void* d_ws, size_t ws_size,
                              hipStream_t stream) {
    const float* logits = (const float*)d_in[0];
    const float* boxes  = (const float*)d_in[1];
    float* out = (float*)d_out;
    int nrows = in_sizes[0] / N_CLS;   // 200000

    char* w = (char*)d_ws;
    unsigned* cnt    = (unsigned*)(w + OFF_CNT);
    unsigned* cnt2   = (unsigned*)(w + OFF_CNT2);
    unsigned* ghist  = (unsigned*)(w + OFF_GH);
    unsigned* rhist  = (unsigned*)(w + OFF_RH);
    u64* sorted      = (u64*)(w + OFF_SORTED);
    u64* sel         = (u64*)(w + OFF_SEL);
    u64* sel2        = (u64*)(w + OFF_SEL2);
    float* boxK      = (float*)(w + OFF_BOX);
    float* scoreK    = (float*)(w + OFF_SCORE);
    int* clsK        = (int*)(w + OFF_CLS);
    u64* mask        = (u64*)(w + OFF_MASK);

    hipMemsetAsync(w, 0, MEMSET_BYTES, stream);

    k_pass1<<<2048, 256, 0, stream>>>(logits, nrows, sel, cnt, ghist);

    void* args[] = {
        (void*)&boxes, (void*)&sel, (void*)&cnt, (void*)&ghist, (void*)&rhist,
        (void*)&sel2, (void*)&cnt2, (void*)&sorted,
        (void*)&boxK, (void*)&scoreK, (void*)&clsK,
        (void*)&mask, (void*)&out
    };
    hipLaunchCooperativeKernel(reinterpret_cast<void*>(k_tail),
                               dim3(256), dim3(1024), args, 0, stream);
}

// Round 4
// 236.196 us; speedup vs baseline: 2.6452x; 2.6452x over previous
//
#include <hip/hip_runtime.h>
#include <stdint.h>
#include <math.h>

#define N_CLS    81
#define TOPK     1000
#define LISTCAP  (1u << 21)     // 2M candidate keys (16 MB)
#define CAP2     65536          // coarse-selected capacity (512 KB)
#define SCORE_TH 0.05f
#define IMG_W    1333.0f
#define IMG_H    800.0f
#define GH_REP   16             // coarse-hist replicas (atomic spread)

// coarse bucket = float_bits >> 19; ghist index = (bits>>19) - GH_BASE in [0,128)
#define GH_BASE  1905

// workspace layout (byte offsets)
#define OFF_CNT    0                       // u32 total candidates
#define OFF_CNT2   8                       // u32 coarse-selected count
#define OFF_GH     64                      // u32[GH_REP][128] coarse hist (8192 B)
#define OFF_RH     8256                    // u32[1024] refined hist
#define OFF_SORTED 12352                   // u64[1000] sorted keys (0 sentinel)
#define MEMSET_BYTES 20352
#define OFF_SEL    20480                   // u64[LISTCAP]
#define OFF_SEL2   16797696                // u64[CAP2]
#define OFF_BOX    17321984                // f32[1000*4]
#define OFF_SCORE  17337984                // f32[1000]
#define OFF_CLS    17341984                // i32[1000]
#define OFF_MASK   17345984                // u64[1000*16] conflict bit matrix

typedef unsigned long long u64;

// ------- K1: single pass: softmax, coarse hist (LDS), compact all p>0.05 -------
// NOTE: arithmetic (loads, butterfly order, expf, e/s) must stay bit-identical
// to the round-1/2 version which matched the reference with absmax 0.0.
__global__ __launch_bounds__(256) void k_pass1(
        const float* __restrict__ logits, int nrows,
        u64* __restrict__ sel, unsigned* __restrict__ cnt,
        unsigned* __restrict__ ghist) {
    __shared__ unsigned lh[128];
    __shared__ u64 cbuf[2048];
    __shared__ unsigned lcnt, gbase;
    int tid = threadIdx.x, wv = tid >> 6, ln = tid & 63;
    for (int i = tid; i < 128; i += 256) lh[i] = 0;
    if (tid == 0) lcnt = 0;
    __syncthreads();

    int stride = gridDim.x * 16;
    for (int base = blockIdx.x * 16 + wv * 4; base < nrows; base += stride) {
        int nr = nrows - base; if (nr > 4) nr = 4;   // wave-uniform
        float v0[4], v1[4], m[4], e0[4], e1[4], s[4];
        #pragma unroll
        for (int k = 0; k < 4; k++) {
            bool ok = (k < nr);
            const float* rp = logits + (size_t)(ok ? base + k : base) * N_CLS;
            v0[k] = ok ? rp[ln] : 0.0f;
            v1[k] = (ok && ln < N_CLS - 64) ? rp[64 + ln] : -INFINITY;
        }
        #pragma unroll
        for (int k = 0; k < 4; k++) m[k] = fmaxf(v0[k], v1[k]);
        #pragma unroll
        for (int off = 32; off > 0; off >>= 1)
            #pragma unroll
            for (int k = 0; k < 4; k++) m[k] = fmaxf(m[k], __shfl_xor(m[k], off));
        #pragma unroll
        for (int k = 0; k < 4; k++) {
            e0[k] = expf(v0[k] - m[k]);
            e1[k] = (ln < N_CLS - 64) ? expf(v1[k] - m[k]) : 0.0f;
            s[k] = e0[k] + e1[k];
        }
        #pragma unroll
        for (int off = 32; off > 0; off >>= 1)
            #pragma unroll
            for (int k = 0; k < 4; k++) s[k] += __shfl_xor(s[k], off);

        #pragma unroll
        for (int k = 0; k < 4; k++) {
            if (k >= nr) break;                     // wave-uniform
            float p0 = e0[k] / s[k];
            float p1 = e1[k] / s[k];
            bool c0 = (k < nr) && (ln != 0) && (p0 > SCORE_TH);
            bool c1 = (k < nr) && (ln < N_CLS - 64) && (p1 > SCORE_TH);
            unsigned fb0 = __float_as_uint(p0), fb1 = __float_as_uint(p1);
            if (c0) atomicAdd(&lh[(fb0 >> 19) - GH_BASE], 1u);
            if (c1) atomicAdd(&lh[(fb1 >> 19) - GH_BASE], 1u);
            u64 b0 = __ballot(c0), b1 = __ballot(c1);
            int n0 = __popcll(b0), n1 = __popcll(b1);
            if (n0 + n1 == 0) continue;
            unsigned wb = 0;
            if (ln == 0) wb = atomicAdd(&lcnt, (unsigned)(n0 + n1));
            wb = __shfl(wb, 0);
            u64 lt = (1ull << ln) - 1ull;
            unsigned flat = (unsigned)(base + k) * N_CLS + (unsigned)ln;
            if (c0) {
                unsigned pos = wb + (unsigned)__popcll(b0 & lt);
                u64 key = ((u64)fb0 << 32) | (u64)(0xFFFFFFu - flat);
                if (pos < 2048) cbuf[pos] = key;
                else { unsigned gp = atomicAdd(cnt, 1u); if (gp < LISTCAP) sel[gp] = key; }
            }
            if (c1) {
                unsigned pos = wb + (unsigned)n0 + (unsigned)__popcll(b1 & lt);
                u64 key = ((u64)fb1 << 32) | (u64)(0xFFFFFFu - (flat + 64u));
                if (pos < 2048) cbuf[pos] = key;
                else { unsigned gp = atomicAdd(cnt, 1u); if (gp < LISTCAP) sel[gp] = key; }
            }
        }
    }
    __syncthreads();
    unsigned* gh = ghist + (blockIdx.x & (GH_REP - 1)) * 128;
    for (int i = tid; i < 128; i += 256) {
        unsigned v = lh[i];
        if (v) atomicAdd(&gh[i], v);
    }
    unsigned total = lcnt; if (total > 2048u) total = 2048u;
    if (tid == 0) gbase = atomicAdd(cnt, total);
    __syncthreads();
    unsigned gb = gbase;
    for (unsigned i = tid; i < total; i += 256) {
        unsigned gp = gb + i;
        if (gp < LISTCAP) sel[gp] = cbuf[i];
    }
}

// ------- K2: coarse select (tb = bucket-B floor) + refined hist, one pass -------
__global__ __launch_bounds__(256) void k_select(
        const u64* __restrict__ sel, const unsigned* __restrict__ cnt,
        const unsigned* __restrict__ ghist, unsigned* __restrict__ rhist,
        u64* __restrict__ sel2, unsigned* __restrict__ cnt2) {
    __shared__ unsigned lh[1024];
    __shared__ unsigned sc0[128], sc1[128];
    __shared__ int sB;
    int tid = threadIdx.x, ln = tid & 63;
    for (int i = tid; i < 1024; i += 256) lh[i] = 0;
    if (tid < 128) {
        unsigned c = 0;
        #pragma unroll
        for (int r = 0; r < GH_REP; r++) c += ghist[r * 128 + tid];
        sc0[tid] = c;
    }
    if (tid == 0) sB = -1;
    __syncthreads();
    unsigned *s0 = sc0, *s1 = sc1;
    for (int off = 1; off < 128; off <<= 1) {
        if (tid < 128) s1[tid] = s0[tid] + ((tid + off < 128) ? s0[tid + off] : 0u);
        __syncthreads();
        unsigned* t = s0; s0 = s1; s1 = t;
    }
    if (tid < 128 && s0[tid] >= TOPK) atomicMax(&sB, tid);
    __syncthreads();
    int B = sB;
    unsigned tb = (B >= 0) ? ((unsigned)(B + GH_BASE) << 19) : 0u;
    unsigned Bb = (unsigned)(B + GH_BASE);

    unsigned M = *cnt; if (M > LISTCAP) M = LISTCAP;
    unsigned gstride = gridDim.x * 256u;
    for (unsigned ib = blockIdx.x * 256u; ib < M; ib += gstride) {
        unsigned i = ib + tid;
        bool act = (i < M);
        u64 key = act ? sel[i] : 0ull;
        unsigned bits = (unsigned)(key >> 32);
        bool c = act && (bits >= tb);
        if (c && B >= 0 && (bits >> 19) == Bb)
            atomicAdd(&lh[(bits >> 9) & 1023u], 1u);
        u64 bal = __ballot(c);
        int n = __popcll(bal);
        if (n) {
            unsigned wb = 0;
            if (ln == 0) wb = atomicAdd(cnt2, (unsigned)n);
            wb = __shfl(wb, 0);
            if (c) {
                unsigned pos = wb + (unsigned)__popcll(bal & ((1ull << ln) - 1ull));
                if (pos < CAP2) sel2[pos] = key;
            }
        }
    }
    __syncthreads();
    for (int i = tid; i < 1024; i += 256) {
        unsigned v = lh[i];
        if (v) atomicAdd(&rhist[i], v);
    }
}

// ------- K3: exact threshold (per-block) + rank by counting + scatter -------
__global__ __launch_bounds__(256) void k_rank(
        const u64* __restrict__ sel2, const unsigned* __restrict__ cnt2,
        const unsigned* __restrict__ ghist, const unsigned* __restrict__ rhist,
        u64* __restrict__ sorted) {
    __shared__ u64 ch[2048];
    __shared__ unsigned sa[256], sb_[256];
    __shared__ int sB, sG;
    __shared__ unsigned tbs;
    int tid = threadIdx.x;

    // coarse bucket B + count strictly above it (parallel suffix scan over 128)
    if (tid < 128) {
        unsigned c = 0;
        #pragma unroll
        for (int r = 0; r < GH_REP; r++) c += ghist[r * 128 + tid];
        sa[tid] = c;
    }
    if (tid == 0) { sB = -1; sG = -1; }
    __syncthreads();
    unsigned *s0 = sa, *s1 = sb_;
    for (int off = 1; off < 128; off <<= 1) {
        if (tid < 128) s1[tid] = s0[tid] + ((tid + off < 128) ? s0[tid + off] : 0u);
        __syncthreads();
        unsigned* t = s0; s0 = s1; s1 = t;
    }
    if (tid < 128 && s0[tid] >= TOPK) atomicMax(&sB, tid);
    __syncthreads();
    int B = sB;
    unsigned c_above = (B >= 0 && B < 127) ? s0[B + 1] : 0u;
    __syncthreads();

    // refined suffix over 256 groups of 4 bins
    unsigned ps = 0;
    #pragma unroll
    for (int k = 0; k < 4; k++) ps += rhist[tid * 4 + k];
    sa[tid] = ps;
    __syncthreads();
    s0 = sa; s1 = sb_;
    for (int off = 1; off < 256; off <<= 1) {
        s1[tid] = s0[tid] + ((tid + off < 256) ? s0[tid + off] : 0u);
        __syncthreads();
        unsigned* t = s0; s0 = s1; s1 = t;
    }
    if (B >= 0 && c_above + s0[tid] >= TOPK) atomicMax(&sG, tid);
    __syncthreads();
    if (tid == 0) {
        unsigned tb = 0;
        if (B >= 0) {
            int g = sG;
            int sbin = 0;
            if (g >= 0) {
                unsigned cab = c_above + ((g < 255) ? s0[g + 1] : 0u);
                for (int i = g * 4 + 3; i >= g * 4; --i) {
                    unsigned c = rhist[i];
                    if (cab + c >= TOPK) { sbin = i; break; }
                    cab += c;
                }
            }
            tb = ((unsigned)(B + GH_BASE) << 19) | ((unsigned)sbin << 9);
        }
        tbs = tb;
    }
    __syncthreads();
    unsigned tb = tbs;

    // rank: count keys > my among keys >= tb (keys < tb contribute 0 anyway)
    unsigned S = *cnt2; if (S > CAP2) S = CAP2;
    unsigned t = blockIdx.x * 256u + tid;
    u64 my = (t < S) ? sel2[t] : 0ull;
    bool active = (t < S) && ((unsigned)(my >> 32) >= tb);
    unsigned r = 0;
    for (unsigned c0 = 0; c0 < S; c0 += 2048) {
        unsigned n = S - c0; if (n > 2048u) n = 2048u;
        __syncthreads();
        for (unsigned i = tid; i < n; i += 256) ch[i] = sel2[c0 + i];
        __syncthreads();
        if (active)
            for (unsigned j = 0; j < n; j++) r += (ch[j] > my) ? 1u : 0u;
    }
    if (active && r < TOPK) sorted[r] = my;
}

// ------- K4: fused decode + conflict bit-matrix -------
__global__ __launch_bounds__(256) void k_conflict(
        const u64* __restrict__ sorted, const float* __restrict__ boxes,
        float* __restrict__ boxK, float* __restrict__ scoreK, int* __restrict__ clsK,
        u64* __restrict__ mask) {
    int t = blockIdx.x * 256 + threadIdx.x;
    if (t >= TOPK * 16) return;
    int i = t >> 4, w = t & 15;
    u64 key = sorted[i];
    float x1 = 0.0f, y1 = 0.0f, x2 = 0.0f, y2 = 0.0f, sc = 0.0f;
    int ci = -1;
    if (key != 0ull) {
        sc = __uint_as_float((unsigned)(key >> 32));
        unsigned fi = 0xFFFFFFu - (unsigned)(key & 0xFFFFFFFFull);
        unsigned prop = fi / N_CLS;
        ci = (int)(fi - prop * N_CLS);
        const float* bp = boxes + (size_t)prop * 4;
        x1 = fminf(fmaxf(bp[0], 0.0f), IMG_W - 1.0f);
        y1 = fminf(fmaxf(bp[1], 0.0f), IMG_H - 1.0f);
        x2 = fminf(fmaxf(bp[2], 0.0f), IMG_W - 1.0f);
        y2 = fminf(fmaxf(bp[3], 0.0f), IMG_H - 1.0f);
    }
    if (w == 0) {
        boxK[i * 4 + 0] = x1; boxK[i * 4 + 1] = y1;
        boxK[i * 4 + 2] = x2; boxK[i * 4 + 3] = y2;
        scoreK[i] = sc;
        clsK[i] = ci;
    }
    float ai = (x2 - x1) * (y2 - y1);
    u64 m = 0;
    int jbase = w << 6;
    for (int jj = 0; jj < 64; jj++) {
        int j = jbase + jj;
        if (j >= TOPK) break;
        u64 kj = sorted[j];
        if (kj == 0ull) continue;
        unsigned fj = 0xFFFFFFu - (unsigned)(kj & 0xFFFFFFFFull);
        unsigned pj = fj / N_CLS;
        int cj = (int)(fj - pj * N_CLS);
        const float* bq = boxes + (size_t)pj * 4;
        float u1 = fminf(fmaxf(bq[0], 0.0f), IMG_W - 1.0f);
        float w1 = fminf(fmaxf(bq[1], 0.0f), IMG_H - 1.0f);
        float u2 = fminf(fmaxf(bq[2], 0.0f), IMG_W - 1.0f);
        float w2 = fminf(fmaxf(bq[3], 0.0f), IMG_H - 1.0f);
        float aj = (u2 - u1) * (w2 - w1);
        float ww = fmaxf(fminf(x2, u2) - fmaxf(x1, u1), 0.0f);
        float hh = fmaxf(fminf(y2, w2) - fmaxf(y1, w1), 0.0f);
        float inter = ww * hh;
        float iou = inter / (ai + aj - inter + 1e-9f);
        if (iou > 0.5f && ci == cj) m |= (1ull << jj);
    }
    mask[(size_t)i * 16 + w] = m;
}

// ------- K5: Jacobi fixed-point of the triangular greedy-NMS recurrence -------
// keep[i] = valid[i] & !OR_{j<i}(keep[j] & conflict[j][i]); unique fixed point.
__global__ __launch_bounds__(1024) void k_nms_out(
        const u64* __restrict__ mask, const float* __restrict__ boxK,
        const float* __restrict__ scoreK, float* __restrict__ out) {
    __shared__ u64 words[16];
    __shared__ int changed;
    int tid = threadIdx.x, wv = tid >> 6, ln = tid & 63;
    bool valid = (tid < TOPK) && (scoreK[tid] > 0.0f);
    u64 row[16];
    #pragma unroll
    for (int w = 0; w < 16; w++)
        row[w] = (tid < TOPK) ? mask[(size_t)tid * 16 + w] : 0ull;
    u64 lowmask = (1ull << ln) - 1ull;
    bool keep = valid;
    for (int it = 0; it < 1024; ++it) {
        u64 b = __ballot(keep);
        if (ln == 0) words[wv] = b;
        if (tid == 0) changed = 0;
        __syncthreads();
        u64 sup = 0;
        for (int w = 0; w <= wv; w++) {          // wv is wave-uniform
            u64 kw = words[w];
            if (w == wv) kw &= lowmask;
            sup |= row[w] & kw;
        }
        bool nk = valid && (sup == 0ull);
        if (nk != keep) changed = 1;
        keep = nk;
        __syncthreads();
        if (!changed) break;
    }
    if (tid < TOPK) {
        float x1 = boxK[tid * 4 + 0], y1 = boxK[tid * 4 + 1];
        float x2 = boxK[tid * 4 + 2], y2 = boxK[tid * 4 + 3];
        float sc = scoreK[tid];
        out[tid * 5 + 0] = keep ? x1 : 0.0f;
        out[tid * 5 + 1] = keep ? y1 : 0.0f;
        out[tid * 5 + 2] = keep ? x2 : 0.0f;
        out[tid * 5 + 3] = keep ? y2 : 0.0f;
        out[tid * 5 + 4] = keep ? sc : 0.0f;
    }
}

extern "C" void kernel_launch(void* const* d_in, const int* in_sizes, int n_in,
                              void* d_out, int out_size, void* d_ws, size_t ws_size,
                              hipStream_t stream) {
    const float* logits = (const float*)d_in[0];
    const float* boxes  = (const float*)d_in[1];
    float* out = (float*)d_out;
    int nrows = in_sizes[0] / N_CLS;   // 200000

    char* w = (char*)d_ws;
    unsigned* cnt    = (unsigned*)(w + OFF_CNT);
    unsigned* cnt2   = (unsigned*)(w + OFF_CNT2);
    unsigned* ghist  = (unsigned*)(w + OFF_GH);
    unsigned* rhist  = (unsigned*)(w + OFF_RH);
    u64* sorted      = (u64*)(w + OFF_SORTED);
    u64* sel         = (u64*)(w + OFF_SEL);
    u64* sel2        = (u64*)(w + OFF_SEL2);
    float* boxK      = (float*)(w + OFF_BOX);
    float* scoreK    = (float*)(w + OFF_SCORE);
    int* clsK        = (int*)(w + OFF_CLS);
    u64* mask        = (u64*)(w + OFF_MASK);

    hipMemsetAsync(w, 0, MEMSET_BYTES, stream);

    k_pass1<<<2048, 256, 0, stream>>>(logits, nrows, sel, cnt, ghist);
    k_select<<<256, 256, 0, stream>>>(sel, cnt, ghist, rhist, sel2, cnt2);
    k_rank<<<CAP2 / 256, 256, 0, stream>>>(sel2, cnt2, ghist, rhist, sorted);
    k_conflict<<<(TOPK * 16 + 255) / 256, 256, 0, stream>>>(sorted, boxes, boxK, scoreK, clsK, mask);
    k_nms_out<<<1, 1024, 0, stream>>>(mask, boxK, scoreK, out);
}